// Round 1
// baseline (890.399 us; speedup 1.0000x reference)
//
#include <hip/hip_runtime.h>
#include <stdint.h>

// Problem constants (from reference setup_inputs)
constexpr int L = 12;
constexpr int B = 16;
constexpr int S = 577;
constexpr int D = 1024;
constexpr int H = 16;
constexpr int N = S - 1;      // 576 spatial tokens
constexpr int K = 115;        // max(1, int(576 * 0.2))
constexpr int SORTN = 1024;   // next pow2 >= N

// ---------------------------------------------------------------------------
// Kernel 1: per-batch scores + top-K via bitonic sort.
// One block per batch b. Scores: sequential fp32 sum over h (matches numpy's
// outer-axis reduction order bit-for-bit), * 1/16 (exact, pow2).
// Sort key packs (sortable float bits, 0xFFFFFFFF - idx) so descending sort
// gives descending score with ascending-index tie-break == jax.lax.top_k.
// ---------------------------------------------------------------------------
__global__ __launch_bounds__(SORTN) void topk_kernel(const float* __restrict__ att,
                                                     int* __restrict__ sel) {
    __shared__ uint64_t keys[SORTN];
    const int b = blockIdx.x;
    const int t = threadIdx.x;

    if (t < N) {
        // att[b, h, 0, 1+t]; row stride over h is S*S
        const float* base = att + (size_t)b * H * S * S + 1 + t;
        float s = 0.0f;
#pragma unroll
        for (int h = 0; h < H; ++h) {
            s += base[(size_t)h * S * S];
        }
        const float score = s * (1.0f / 16.0f);
        uint32_t fb = __float_as_uint(score);
        // float -> order-preserving uint (handles negatives for safety)
        fb = (fb & 0x80000000u) ? ~fb : (fb | 0x80000000u);
        keys[t] = ((uint64_t)fb << 32) | (uint64_t)(0xFFFFFFFFu - (uint32_t)t);
    } else {
        keys[t] = 0ull;  // -inf pad
    }
    __syncthreads();

    // Bitonic sort, descending
    for (int k = 2; k <= SORTN; k <<= 1) {
        for (int j = k >> 1; j > 0; j >>= 1) {
            const int ixj = t ^ j;
            if (ixj > t) {
                const uint64_t a = keys[t];
                const uint64_t c = keys[ixj];
                const bool desc = ((t & k) == 0);
                if (desc ? (a < c) : (a > c)) {
                    keys[t] = c;
                    keys[ixj] = a;
                }
            }
            __syncthreads();
        }
    }

    if (t < K) {
        sel[b * K + t] = (int)(0xFFFFFFFFu - (uint32_t)(keys[t] & 0xFFFFFFFFull));
    }
}

// ---------------------------------------------------------------------------
// Kernel 2: gather selected rows of key_states and value_states.
// One block per (l, b, r) output row; 256 threads x float4 == 1024 floats.
// Copies both the key row and the value row (8 KB traffic per block).
// ---------------------------------------------------------------------------
__global__ __launch_bounds__(256) void gather_kernel(const float4* __restrict__ key,
                                                     const float4* __restrict__ val,
                                                     const int* __restrict__ sel,
                                                     float4* __restrict__ outk,
                                                     float4* __restrict__ outv) {
    const int row = blockIdx.x;          // (l*B + b)*K + r
    const int r   = row % K;
    const int lb  = row / K;             // l*B + b
    const int b   = lb % B;

    const int srow = 1 + sel[b * K + r]; // +1: spatial tokens start at index 1
    constexpr int D4 = D / 4;            // 256 float4 per row

    const size_t src = ((size_t)lb * S + (size_t)srow) * D4 + threadIdx.x;
    const size_t dst = (size_t)row * D4 + threadIdx.x;

    outk[dst] = key[src];
    outv[dst] = val[src];
}

extern "C" void kernel_launch(void* const* d_in, const int* in_sizes, int n_in,
                              void* d_out, int out_size, void* d_ws, size_t ws_size,
                              hipStream_t stream) {
    const float* key = (const float*)d_in[0];   // (L, B, S, D)
    const float* val = (const float*)d_in[1];   // (L, B, S, D)
    const float* att = (const float*)d_in[2];   // (B, H, S, S)
    float* out = (float*)d_out;                 // selected_keys ++ selected_values
    int* sel = (int*)d_ws;                      // B*K ints

    topk_kernel<<<B, SORTN, 0, stream>>>(att, sel);

    const size_t out_stride = (size_t)L * B * K * D;  // elements in selected_keys
    gather_kernel<<<L * B * K, 256, 0, stream>>>(
        (const float4*)key, (const float4*)val, sel,
        (float4*)out, (float4*)(out + out_stride));
}